// Round 17
// baseline (121.328 us; speedup 1.0000x reference)
//
#include <hip/hip_runtime.h>
#include <hip/hip_bf16.h>

typedef float  f32x4  __attribute__((ext_vector_type(4)));
typedef __bf16 bf16x8 __attribute__((ext_vector_type(8)));
typedef unsigned int   u32;
typedef unsigned short u16;
typedef u32   u32x2  __attribute__((ext_vector_type(2)));
typedef u32   u32x4  __attribute__((ext_vector_type(4)));
typedef u16   u16x4  __attribute__((ext_vector_type(4)));
typedef u16   u16x8  __attribute__((ext_vector_type(8)));

#define DEV __device__ __forceinline__

constexpr int NB = 8, T = 2048, C = 1024, H = 128;
constexpr int BT = NB * T;

union Frag {
  bf16x8 v;
  u32x4  u4;
  u32x2  u2[2];
  u32    u[4];
  u16    s[8];
};

DEV u16 f2bu(float f) {
  __hip_bfloat16 h = __float2bfloat16(f);
  return __builtin_bit_cast(u16, h);
}
DEV float bu2f(u16 u) {
  return __bfloat162float(__builtin_bit_cast(__hip_bfloat16, u));
}
DEV f32x4 MFMA(bf16x8 a, bf16x8 b, f32x4 c) {
  return __builtin_amdgcn_mfma_f32_16x16x32_bf16(a, b, c, 0, 0, 0);
}

// Async global->LDS DMA, 16B per lane: per-lane GLOBAL source address,
// wave-uniform LDS base (HW adds lane*16).
DEV void gload16(const void* g, void* l) {
  __builtin_amdgcn_global_load_lds(
      (const __attribute__((address_space(1))) void*)g,
      (__attribute__((address_space(3))) void*)l, 16, 0, 0);
}

// ---------------------------------------------------------------------------
// Lane-contiguous fragment layouts (16B/lane, 1KB/wave per load):
//   wpq/wpk: [tt8][kc32][hl2][lane64][e8]        (tile-kc stride 1024 u16)
//   wpv:     [tt8][kc32][lane64][e8]             (512)
//   qpk/kpk: [b8][tile128][hs4][hl2][lane64][e8] (tile stride 4096)
//   vpk:     [b8][kt64][ht8][lane64][e8]         (kt stride 4096)
// ---------------------------------------------------------------------------

__global__ void prep_w(const float* __restrict__ Wk, const float* __restrict__ Wq,
                       const float* __restrict__ Wv,
                       u16* __restrict__ wpq, u16* __restrict__ wpk,
                       u16* __restrict__ wpv) {
  const int id = blockIdx.x * 256 + threadIdx.x;   // 24*32*64 = 49152
  if (id >= 24 * 32 * 64) return;
  const int lane = id & 63;
  const int kc   = (id >> 6) & 31;
  const int tile = id >> 11;          // 0..23
  const int mat  = tile >> 3;         // 0=q 1=k 2=v
  const int tt   = tile & 7;
  const int n    = tt * 16 + (lane & 15);
  const float* W = (mat == 0) ? Wq : (mat == 1) ? Wk : Wv;
  u16x8 hi, lo;
  #pragma unroll
  for (int e = 0; e < 8; ++e) {
    const int k = kc * 32 + 4 * (lane >> 4) + (e & 3) + 16 * (e >> 2);
    const float w = W[(size_t)k * H + n];
    u16 h = f2bu(w);
    hi[e] = h;
    lo[e] = f2bu(w - bu2f(h));
  }
  if (mat == 2) {
    *(u16x8*)(wpv + ((size_t)(tt * 32 + kc) * 64 + lane) * 8) = hi;
  } else {
    u16* p = ((mat == 0) ? wpq : wpk) +
             (((size_t)(tt * 32 + kc) * 2 + 0) * 64 + lane) * 8;
    *(u16x8*)p         = hi;
    *(u16x8*)(p + 512) = lo;
  }
}

// ---------------------------------------------------------------------------
// Kernel 1: projections v13. BM=64, 8 waves; wave = (ms = w&3 -> rows
// 16ms..16ms+15, nh = w>>2 -> 1q+1k+1v tiles of n-group ng).
//  - x staged as RAW F32 via global_load_lds (1 DMA instr/wave/step; no
//    writeX, no x registers, no staging cvt). Conversion to bf16 hi/lo at
//    the consumer. Chunk layout: chunk w = rows 16(w>>1)+(l&15), cols
//    16(w&1)+4(l>>4); A-frag read = 2 conflict-free ds_read_b128 at
//    lane' = lc+16lg.
//  - W reg-staged double-buffer (r14-proven).
//  - LDS 36.9 KB; launch_bounds(512,6) (VGPR<=85, not starved).
//  - r16-proven grid swizzle: mt=(bid>>5)*8+(bid&7), ng=(bid>>3)&3
//    (FETCH 40 MB: x-sharers co-resident on same XCD).
// ---------------------------------------------------------------------------
__global__ __launch_bounds__(512, 6) void proj_kernel(
    const float* __restrict__ x,
    const u16* __restrict__ wpq, const u16* __restrict__ wpk,
    const u16* __restrict__ wpv,
    u16* __restrict__ qpk, u16* __restrict__ kpk, u16* __restrict__ vpk) {
  __shared__ float xls[2][2048];           // 16.4 KB: [buf][chunk8][lane64][4]
  __shared__ u16 wsl[2][640 * 8];          // 20.5 KB
  const int tid  = threadIdx.x;            // 0..511
  const int bid  = blockIdx.x;
  const int mt   = (bid >> 5) * 8 + (bid & 7);   // 0..255
  const int ng   = (bid >> 3) & 3;               // 0..3
  const int m0   = mt * 64;
  const int w    = tid >> 6;               // 0..7
  const int lane = tid & 63;
  const int lg   = lane >> 4, lc = lane & 15;
  const int ms   = w & 3;                  // rows 16ms..16ms+15
  const int nh   = w >> 2;                 // tile tt = 2ng+nh

  // x DMA source for this wave's chunk (chunk id = w), ks-invariant part:
  // lane reads x[m0 + 16*(w>>1) + (l&15)][ks*32 + 16*(w&1) + 4*(l>>4) ...+3]
  const float* xg = x + (size_t)(m0 + 16 * (w >> 1) + lc) * C
                      + 16 * (w & 1) + 4 * lg;

  // ---- hoisted W staging coords: 640 chunks = 10 planes x 64 lanes;
  // planes: 0-3 q(jt,hl), 4-7 k(jt,hl), 8-9 v(jt). 2 rounds of 512 threads.
  const u16* wbase[2];
  int wstep[2], wofs[2];
  bool wact[2];
  #pragma unroll
  for (int i = 0; i < 2; ++i) {
    const int c = tid + 512 * i;
    wact[i] = (c < 640);
    const int cc = wact[i] ? c : 0;
    const int p  = cc >> 6;
    const int ln = cc & 63;
    const u16* base;
    int stride;
    if (p < 4) {
      base = wpq + (size_t)((2 * ng + (p >> 1)) * 32) * 1024 + (p & 1) * 512 + ln * 8;
      stride = 1024;
    } else if (p < 8) {
      base = wpk + (size_t)((2 * ng + ((p - 4) >> 1)) * 32) * 1024 + ((p - 4) & 1) * 512 + ln * 8;
      stride = 1024;
    } else {
      base = wpv + (size_t)((2 * ng + (p - 8)) * 32) * 512 + ln * 8;
      stride = 512;
    }
    wbase[i] = base;
    wstep[i] = stride;
    wofs[i]  = (p * 64 + ln) * 8;
  }

  f32x4 zero = {0.f, 0.f, 0.f, 0.f};
  f32x4 acc[3];                            // q, k, v
  #pragma unroll
  for (int j = 0; j < 3; ++j) acc[j] = zero;

  u16x8 wreg[2];

  auto gloadX = [&](int ks, int buf) {     // one DMA instruction per wave
    const int k = ks > 31 ? 31 : ks;
    gload16(xg + (size_t)k * 32, &xls[buf][w * 256]);
  };
  auto loadW = [&](int ks) {
    const int k = ks > 31 ? 31 : ks;
    #pragma unroll
    for (int i = 0; i < 2; ++i)
      if (wact[i]) wreg[i] = *(const u16x8*)(wbase[i] + (size_t)k * wstep[i]);
  };
  auto writeW = [&](int buf) {
    #pragma unroll
    for (int i = 0; i < 2; ++i)
      if (wact[i]) *(u16x8*)&wsl[buf][wofs[i]] = wreg[i];
  };

  auto compute = [&](int buf) {
    // x f32 frags -> cvt to hi/lo bf16
    const f32x4 x0 = *(const f32x4*)&xls[buf][(ms * 2 + 0) * 256 + (lc + 16 * lg) * 4];
    const f32x4 x1 = *(const f32x4*)&xls[buf][(ms * 2 + 1) * 256 + (lc + 16 * lg) * 4];
    Frag axh, axl;
    #pragma unroll
    for (int e = 0; e < 4; ++e) {
      u16 h0 = f2bu(x0[e]);
      axh.s[e] = h0;  axl.s[e] = f2bu(x0[e] - bu2f(h0));
      u16 h1 = f2bu(x1[e]);
      axh.s[e + 4] = h1;  axl.s[e + 4] = f2bu(x1[e] - bu2f(h1));
    }
    Frag qh, ql, kh, kl, vh;
    qh.u4 = *(const u32x4*)&wsl[buf][((0 + nh * 2 + 0) * 64 + lane) * 8];
    ql.u4 = *(const u32x4*)&wsl[buf][((0 + nh * 2 + 1) * 64 + lane) * 8];
    kh.u4 = *(const u32x4*)&wsl[buf][((4 + nh * 2 + 0) * 64 + lane) * 8];
    kl.u4 = *(const u32x4*)&wsl[buf][((4 + nh * 2 + 1) * 64 + lane) * 8];
    vh.u4 = *(const u32x4*)&wsl[buf][((8 + nh) * 64 + lane) * 8];
    acc[0] = MFMA(axh.v, qh.v, acc[0]);
    acc[0] = MFMA(axh.v, ql.v, acc[0]);
    acc[0] = MFMA(axl.v, qh.v, acc[0]);
    acc[1] = MFMA(axh.v, kh.v, acc[1]);
    acc[1] = MFMA(axh.v, kl.v, acc[1]);
    acc[1] = MFMA(axl.v, kh.v, acc[1]);
    acc[2] = MFMA(axh.v, vh.v, acc[2]);
  };

  // prologue: x(0) DMA -> buf0; W(0) regs -> wsl0; W(1) -> regs
  gloadX(0, 0);
  loadW(0);
  writeW(0);
  loadW(1);
  __syncthreads();                         // drains x(0) DMA + W writes
  for (int ks = 0; ks < 32; ++ks) {
    const int cur = ks & 1;
    gloadX(ks + 1, cur ^ 1);               // async DMA into idle buffer
    writeW(cur ^ 1);                       // W(ks+1) from regs
    loadW(ks + 2);                         // W(ks+2) -> regs (in flight)
    compute(cur);                          // 7 MFMA
    __syncthreads();                       // publishes buf^1 (drains DMA)
  }

  // Epilogue (r15-verified): value = Out[m0 + 16ms + 4lg + r][tt*16 + lc]
  const int tt = 2 * ng + nh;
  const int tb_abs = mt * 4 + ms;
  const int b  = tb_abs >> 7;
  const int tb = tb_abs & 127;
  const int hs = tt >> 1;
  const int e  = (lc & 3) + 4 * (tt & 1);
  #pragma unroll
  for (int r = 0; r < 4; ++r) {
    const int lane_c = 4 * lg + r + 16 * (lc >> 2);
    // q
    {
      const float val = acc[0][r];
      const u16 hvv = f2bu(val);
      u16* dst = qpk + (((size_t)(b * 128 + tb) * 4 + hs) * 2 * 64 + lane_c) * 8 + e;
      dst[0]   = hvv;
      dst[512] = f2bu(val - bu2f(hvv));
    }
    // k
    {
      const float val = acc[1][r];
      const u16 hvv = f2bu(val);
      u16* dst = kpk + (((size_t)(b * 128 + tb) * 4 + hs) * 2 * 64 + lane_c) * 8 + e;
      dst[0]   = hvv;
      dst[512] = f2bu(val - bu2f(hvv));
    }
    // v
    {
      const int kt = tb >> 1;
      const int lane_cv = lc + 16 * lg;
      const int ev = r + 4 * (tb & 1);
      vpk[(((size_t)(b * 64 + kt) * 8 + tt) * 64 + lane_cv) * 8 + ev] = f2bu(acc[2][r]);
    }
  }
}

// ---------------------------------------------------------------------------
// Kernel 2: causal flash attention (round-4 structure + setprio on MFMA
// clusters). 8 waves, intra-block split-K (kb = w mod 8), 1 q-tile/wave.
// Swapped QK^T so P lands in PV's A-operand layout. LDS combine (bf16).
// ---------------------------------------------------------------------------
__global__ __launch_bounds__(512, 4) void attn_kernel(
    const u16* __restrict__ qpk, const u16* __restrict__ kpk,
    const u16* __restrict__ vpk, float* __restrict__ out) {
  __shared__ float lm[8][16];
  __shared__ float ll[8][16];
  __shared__ u16 lo[8][16][132];     // bf16 partial O

  const int bid = blockIdx.x;
  const int b   = bid & 7;           // batch -> XCD affinity
  const int qt  = bid >> 3;          // 0..127
  const int w    = threadIdx.x >> 6;
  const int lane = threadIdx.x & 63;
  const int lg = lane >> 4, lc = lane & 15;

  // Q fragments: [b][qt][hs][hl][lane][8], tile stride 4096 u16
  Frag bqh[4], bql[4];
  const u16* qp = qpk + (size_t)(b * 128 + qt) * 4096 + lane * 8;
  #pragma unroll
  for (int hs = 0; hs < 4; ++hs) {
    bqh[hs].u4 = *(const u32x4*)(qp + (size_t)(hs * 2 + 0) * 512);
    bql[hs].u4 = *(const u32x4*)(qp + (size_t)(hs * 2 + 1) * 512);
  }

  f32x4 zero = {0.f, 0.f, 0.f, 0.f};
  f32x4 o_acc[8];
  #pragma unroll
  for (int i = 0; i < 8; ++i) o_acc[i] = zero;
  float m_run = -INFINITY, l_run = 0.f;

  const int myq = qt * 16 + lc;
  const int nkb = qt >> 2;           // last 64-wide k-block

  for (int kb = w; kb <= nkb; kb += 8) {
    f32x4 s[4];
    #pragma unroll
    for (int t = 0; t < 4; ++t) s[t] = zero;

    const u16* kp = kpk + (size_t)(b * 128 + kb * 4) * 4096 + lane * 8;
    __builtin_amdgcn_s_setprio(1);
    #pragma unroll
    for (int t = 0; t < 4; ++t) {
      #pragma unroll
      for (int hs = 0; hs < 4; ++hs) {
        const u16* p = kp + (size_t)(t * 8 + hs * 2) * 512;
        Frag akh, akl;
        akh.u4 = *(const u32x4*)p;
        akl.u4 = *(const u32x4*)(p + 512);
        s[t] = MFMA(akh.v, bqh[hs].v, s[t]);
        s[t] = MFMA(akh.v, bql[hs].v, s[t]);
        s[t] = MFMA(akl.v, bqh[hs].v, s[t]);
      }
    }
    __builtin_amdgcn_s_setprio(0);

    // scale by sqrt(C)=32; causal + (tril==0 -> -inf) semantics
    float pmax = -INFINITY;
    #pragma unroll
    for (int t = 0; t < 4; ++t) {
      #pragma unroll
      for (int r = 0; r < 4; ++r) {
        const int kk = kb * 64 + t * 16 + 4 * lg + r;
        float v = s[t][r] * 32.0f;
        if (kk > myq || v == 0.0f) v = -INFINITY;
        s[t][r] = v;
        pmax = fmaxf(pmax, v);
      }
    }
    pmax = fmaxf(pmax, __shfl_xor(pmax, 16));
    pmax = fmaxf(pmax, __shfl_xor(pmax, 32));
    const float m_new = fmaxf(m_run, pmax);
    const float alpha = __expf(m_run - m_new);

    float sum = 0.f;
    u16 pb[16];
    #pragma unroll
    for (int t = 0; t < 4; ++t) {
      #pragma unroll
      for (int r = 0; r < 4; ++r) {
        const float p = __expf(s[t][r] - m_new);
        sum += p;
        pb[t * 4 + r] = f2bu(p);
      }
    }
    sum += __shfl_xor(sum, 16);
    sum += __shfl_xor(sum, 32);
    l_run = l_run * alpha + sum;
    m_run = m_new;

    float al[4];
    #pragma unroll
    for (int r = 0; r < 4; ++r) al[r] = __shfl(alpha, 4 * lg + r);
    #pragma unroll
    for (int i = 0; i < 8; ++i) {
      #pragma unroll
      for (int r = 0; r < 4; ++r) o_acc[i][r] *= al[r];
    }

    Frag pa[2];
    #pragma unroll
    for (int ks = 0; ks < 2; ++ks) {
      #pragma unroll
      for (int e = 0; e < 8; ++e)
        pa[ks].s[e] = pb[(2 * ks + (e >> 2)) * 4 + (e & 3)];
    }

    __builtin_amdgcn_s_setprio(1);
    #pragma unroll
    for (int ks = 0; ks < 2; ++ks) {
      const u16* vp = vpk + (size_t)(b * 64 + kb * 2 + ks) * 4096 + lane * 8;
      #pragma unroll
      for (int ht = 0; ht < 8; ++ht) {
        Frag bv;
        bv.u4 = *(const u32x4*)(vp + (size_t)ht * 512);
        o_acc[ht] = MFMA(pa[ks].v, bv.v, o_acc[ht]);
      }
    }
    __builtin_amdgcn_s_setprio(0);
  }

  // --- combine 8 partials through LDS ---
  if (lane < 16) { lm[w][lane] = m_run; ll[w][lane] = l_run; }
  #pragma unroll
  for (int ht = 0; ht < 8; ++ht)
    #pragma unroll
    for (int r = 0; r < 4; ++r)
      lo[w][4 * lg + r][ht * 16 + lc] = f2bu(o_acc[ht][r]);
  __syncthreads();

  const int tid = threadIdx.x;
  const int q  = tid >> 5;            // 0..15
  const int hb = (tid & 31) * 4;      // 0..124
  float M = -INFINITY;
  #pragma unroll
  for (int ww = 0; ww < 8; ++ww) M = fmaxf(M, lm[ww][q]);
  float lsum = 0.f;
  f32x4 osum = {0.f, 0.f, 0.f, 0.f};
  #pragma unroll
  for (int ww = 0; ww < 8; ++ww) {
    const float sc = __expf(lm[ww][q] - M);
    lsum += sc * ll[ww][q];
    const u16x4 ov = *(const u16x4*)&lo[ww][q][hb];
    #pragma unroll
    for (int j = 0; j < 4; ++j) osum[j] += sc * bu2f(ov[j]);
  }
  const float inv = 1.0f / lsum;
  f32x4 res = {osum[0] * inv, osum[1] * inv, osum[2] * inv, osum[3] * inv};
  *(f32x4*)&out[((size_t)(b * T + qt * 16 + q)) * H + hb] = res;
}

// ---------------------------------------------------------------------------
extern "C" void kernel_launch(void* const* d_in, const int* in_sizes, int n_in,
                              void* d_out, int out_size, void* d_ws, size_t ws_size,
                              hipStream_t stream) {
  (void)in_sizes; (void)n_in; (void)out_size; (void)ws_size;
  const float* x  = (const float*)d_in[0];
  const float* Wk = (const float*)d_in[1];
  const float* Wq = (const float*)d_in[2];
  const float* Wv = (const float*)d_in[3];
  float* out = (float*)d_out;

  u16* w = (u16*)d_ws;
  const size_t WPQK = (size_t)8 * 32 * 2 * 64 * 8;       // 262144
  const size_t WPV  = (size_t)8 * 32 * 64 * 8;           // 131072
  const size_t QKP  = (size_t)NB * 128 * 4 * 2 * 64 * 8; // 4194304
  u16* wpq = w;
  u16* wpk = wpq + WPQK;
  u16* wpv = wpk + WPQK;
  u16* qpk = wpv + WPV;
  u16* kpk = qpk + QKP;
  u16* vpk = kpk + QKP;

  prep_w<<<192, 256, 0, stream>>>(Wk, Wq, Wv, wpq, wpk, wpv);
  proj_kernel<<<1024, 512, 0, stream>>>(x, wpq, wpk, wpv, qpk, kpk, vpk);
  attn_kernel<<<NB * (T / 16), 512, 0, stream>>>(qpk, kpk, vpk, out);
}

// Round 19
// 100.217 us; speedup vs baseline: 1.2106x; 1.2106x over previous
//
#include <hip/hip_runtime.h>
#include <hip/hip_bf16.h>

typedef float  f32x4  __attribute__((ext_vector_type(4)));
typedef __bf16 bf16x8 __attribute__((ext_vector_type(8)));
typedef unsigned int   u32;
typedef unsigned short u16;
typedef u32   u32x2  __attribute__((ext_vector_type(2)));
typedef u32   u32x4  __attribute__((ext_vector_type(4)));
typedef u16   u16x4  __attribute__((ext_vector_type(4)));
typedef u16   u16x8  __attribute__((ext_vector_type(8)));

#define DEV __device__ __forceinline__

constexpr int NB = 8, T = 2048, C = 1024, H = 128;
constexpr int BT = NB * T;

union Frag {
  bf16x8 v;
  u32x4  u4;
  u32x2  u2[2];
  u32    u[4];
  u16    s[8];
};

DEV u16 f2bu(float f) {
  __hip_bfloat16 h = __float2bfloat16(f);
  return __builtin_bit_cast(u16, h);
}
DEV float bu2f(u16 u) {
  return __bfloat162float(__builtin_bit_cast(__hip_bfloat16, u));
}
DEV f32x4 MFMA(bf16x8 a, bf16x8 b, f32x4 c) {
  return __builtin_amdgcn_mfma_f32_16x16x32_bf16(a, b, c, 0, 0, 0);
}

// Barrier WITHOUT the vmcnt(0) drain __syncthreads would emit: LDS ops must
// be complete (lgkmcnt(0)) for cross-wave visibility, but global loads feed
// REGISTERS here — the compiler's counted vmcnt before their use suffices.
DEV void bar_lds_only() {
  asm volatile("s_waitcnt lgkmcnt(0)" ::: "memory");
  __builtin_amdgcn_s_barrier();
  __builtin_amdgcn_sched_barrier(0);
}

// ---------------------------------------------------------------------------
// Lane-contiguous fragment layouts (16B/lane, 1KB/wave per load):
//   wpq/wpk: [tt8][kc32][hl2][lane64][e8]        (tile-kc stride 1024 u16)
//   wpv:     [tt8][kc32][lane64][e8]             (512)
//   qpk/kpk: [b8][tile128][hs4][hl2][lane64][e8] (tile stride 4096)
//   vpk:     [b8][kt64][ht8][lane64][e8]         (kt stride 4096)
// ---------------------------------------------------------------------------

__global__ void prep_w(const float* __restrict__ Wk, const float* __restrict__ Wq,
                       const float* __restrict__ Wv,
                       u16* __restrict__ wpq, u16* __restrict__ wpk,
                       u16* __restrict__ wpv) {
  const int id = blockIdx.x * 256 + threadIdx.x;   // 24*32*64 = 49152
  if (id >= 24 * 32 * 64) return;
  const int lane = id & 63;
  const int kc   = (id >> 6) & 31;
  const int tile = id >> 11;          // 0..23
  const int mat  = tile >> 3;         // 0=q 1=k 2=v
  const int tt   = tile & 7;
  const int n    = tt * 16 + (lane & 15);
  const float* W = (mat == 0) ? Wq : (mat == 1) ? Wk : Wv;
  u16x8 hi, lo;
  #pragma unroll
  for (int e = 0; e < 8; ++e) {
    const int k = kc * 32 + 4 * (lane >> 4) + (e & 3) + 16 * (e >> 2);
    const float w = W[(size_t)k * H + n];
    u16 h = f2bu(w);
    hi[e] = h;
    lo[e] = f2bu(w - bu2f(h));
  }
  if (mat == 2) {
    *(u16x8*)(wpv + ((size_t)(tt * 32 + kc) * 64 + lane) * 8) = hi;
  } else {
    u16* p = ((mat == 0) ? wpq : wpk) +
             (((size_t)(tt * 32 + kc) * 2 + 0) * 64 + lane) * 8;
    *(u16x8*)p         = hi;
    *(u16x8*)(p + 512) = lo;
  }
}

// ---------------------------------------------------------------------------
// Kernel 1: projections (r14 config — best measured, 55.7 us) + r16 grid
// swizzle (FETCH 48->40 MB). 8-wave blocks, BM=128; wave = (ms = w&3 ->
// rows 32ms..32ms+31, nh = w>>2 -> 1q+1k+1v tiles). x+W double-buffered in
// LDS, loads issued one step ahead (stay in flight across the drain-free
// barrier), single barrier per K-step.
// Grid 512: mt = (bid>>5)*8 + (bid&7) (0..127), ng = (bid>>3)&3 —
// bijective; XCD = mt%8; all 4 ng of an mt dispatch within 32 bids ->
// x-sharers temporally co-resident on one XCD.
// ---------------------------------------------------------------------------
__global__ __launch_bounds__(512, 4) void proj_kernel(
    const float* __restrict__ x,
    const u16* __restrict__ wpq, const u16* __restrict__ wpk,
    const u16* __restrict__ wpv,
    u16* __restrict__ qpk, u16* __restrict__ kpk, u16* __restrict__ vpk) {
  __shared__ u16 xh[2][128][36];       // 18.4 KB
  __shared__ u16 xl[2][128][36];       // 18.4 KB
  __shared__ u16 wsl[2][640 * 8];      // 20.5 KB: [plane10][lane64][e8]
  const int tid  = threadIdx.x;            // 0..511
  const int bid  = blockIdx.x;
  const int mt   = (bid >> 5) * 8 + (bid & 7);   // 0..127
  const int ng   = (bid >> 3) & 3;               // 0..3
  const int m0   = mt * 128;
  const int w    = tid >> 6;               // 0..7
  const int lane = tid & 63;
  const int lg   = lane >> 4, lc = lane & 15;
  const int ms   = w & 3;                  // rows 32ms..32ms+31
  const int nh   = w >> 2;                 // n-half: tile tt = 2ng+nh

  // ---- hoisted W staging coords: 640 chunks = 10 planes x 64 lanes;
  // planes: 0-3 q(jt,hl), 4-7 k(jt,hl), 8-9 v(jt). 2 rounds of 512 threads.
  const u16* wbase[2];
  int wstep[2], wofs[2];
  bool wact[2];
  #pragma unroll
  for (int i = 0; i < 2; ++i) {
    const int c = tid + 512 * i;
    wact[i] = (c < 640);
    const int cc = wact[i] ? c : 0;
    const int p  = cc >> 6;
    const int ln = cc & 63;
    const u16* base;
    int stride;
    if (p < 4) {
      base = wpq + (size_t)((2 * ng + (p >> 1)) * 32) * 1024 + (p & 1) * 512 + ln * 8;
      stride = 1024;
    } else if (p < 8) {
      base = wpk + (size_t)((2 * ng + ((p - 4) >> 1)) * 32) * 1024 + ((p - 4) & 1) * 512 + ln * 8;
      stride = 1024;
    } else {
      base = wpv + (size_t)((2 * ng + (p - 8)) * 32) * 512 + ln * 8;
      stride = 512;
    }
    wbase[i] = base;
    wstep[i] = stride;
    wofs[i]  = (p * 64 + ln) * 8;
  }

  f32x4 zero = {0.f, 0.f, 0.f, 0.f};
  // named accumulators (declared BEFORE the lambdas that capture them)
  f32x4 accq0 = zero, accq1 = zero, acck0 = zero, acck1 = zero,
        accv0 = zero, accv1 = zero;

  f32x4 xreg[2];
  u16x8 wreg[2];

  auto loadX = [&](int ks) {
    const int k = ks > 31 ? 31 : ks;
    #pragma unroll
    for (int j = 0; j < 2; ++j) {
      const int idx = tid + 512 * j;       // 0..1023
      const int row = idx >> 3;
      const int c4  = (idx & 7) * 4;
      xreg[j] = *(const f32x4*)&x[(size_t)(m0 + row) * C + k * 32 + c4];
    }
  };
  auto writeX = [&](int buf) {
    #pragma unroll
    for (int j = 0; j < 2; ++j) {
      const int idx = tid + 512 * j;
      const int row = idx >> 3;
      const int c4  = (idx & 7) * 4;
      u16x4 hv, lv;
      #pragma unroll
      for (int e = 0; e < 4; ++e) {
        u16 h = f2bu(xreg[j][e]);
        hv[e] = h;
        lv[e] = f2bu(xreg[j][e] - bu2f(h));
      }
      *(u16x4*)&xh[buf][row][c4] = hv;
      *(u16x4*)&xl[buf][row][c4] = lv;
    }
  };
  auto loadW = [&](int ks) {
    const int k = ks > 31 ? 31 : ks;
    #pragma unroll
    for (int i = 0; i < 2; ++i)
      if (wact[i]) wreg[i] = *(const u16x8*)(wbase[i] + (size_t)k * wstep[i]);
  };
  auto writeW = [&](int buf) {
    #pragma unroll
    for (int i = 0; i < 2; ++i)
      if (wact[i]) *(u16x8*)&wsl[buf][wofs[i]] = wreg[i];
  };

  auto compute = [&](int buf) {
    Frag axh[2], axl[2];
    #pragma unroll
    for (int s = 0; s < 2; ++s) {
      const int row = 32 * ms + 16 * s + lc;
      axh[s].u2[0] = *(const u32x2*)&xh[buf][row][4 * lg];
      axh[s].u2[1] = *(const u32x2*)&xh[buf][row][16 + 4 * lg];
      axl[s].u2[0] = *(const u32x2*)&xl[buf][row][4 * lg];
      axl[s].u2[1] = *(const u32x2*)&xl[buf][row][16 + 4 * lg];
    }
    Frag qh, ql, kh, kl, vh;
    qh.u4 = *(const u32x4*)&wsl[buf][((0 + nh * 2 + 0) * 64 + lane) * 8];
    ql.u4 = *(const u32x4*)&wsl[buf][((0 + nh * 2 + 1) * 64 + lane) * 8];
    kh.u4 = *(const u32x4*)&wsl[buf][((4 + nh * 2 + 0) * 64 + lane) * 8];
    kl.u4 = *(const u32x4*)&wsl[buf][((4 + nh * 2 + 1) * 64 + lane) * 8];
    vh.u4 = *(const u32x4*)&wsl[buf][((8 + nh) * 64 + lane) * 8];
    // two independent m-subtile chains interleaved
    accq0 = MFMA(axh[0].v, qh.v, accq0);
    accq1 = MFMA(axh[1].v, qh.v, accq1);
    accq0 = MFMA(axh[0].v, ql.v, accq0);
    accq1 = MFMA(axh[1].v, ql.v, accq1);
    accq0 = MFMA(axl[0].v, qh.v, accq0);
    accq1 = MFMA(axl[1].v, qh.v, accq1);
    acck0 = MFMA(axh[0].v, kh.v, acck0);
    acck1 = MFMA(axh[1].v, kh.v, acck1);
    acck0 = MFMA(axh[0].v, kl.v, acck0);
    acck1 = MFMA(axh[1].v, kl.v, acck1);
    acck0 = MFMA(axl[0].v, kh.v, acck0);
    acck1 = MFMA(axl[1].v, kh.v, acck1);
    accv0 = MFMA(axh[0].v, vh.v, accv0);
    accv1 = MFMA(axh[1].v, vh.v, accv1);
  };

  // prologue: buf0 = step 0; regs = step 1
  loadX(0); loadW(0);
  writeX(0); writeW(0);
  loadX(1); loadW(1);
  bar_lds_only();
  int cur = 0;
  for (int ks = 0; ks < 32; ++ks) {
    writeX(cur ^ 1);                 // regs hold step ks+1 -> idle buffer
    writeW(cur ^ 1);
    loadX(ks + 2);                   // loads stay in flight across the barrier
    loadW(ks + 2);
    compute(cur);                    // 14 MFMA from buf[cur]
    bar_lds_only();                  // single drain-free barrier per K-step
    cur ^= 1;
  }

  // Epilogue: value = Out[m0 + 32ms + 16s + 4lg + r][tt*16 + lc]
  const int tt = 2 * ng + nh;
  const f32x4 aq[2] = {accq0, accq1};
  const f32x4 ak[2] = {acck0, acck1};
  const f32x4 av[2] = {accv0, accv1};
  #pragma unroll
  for (int s = 0; s < 2; ++s) {
    const int tb_abs = mt * 8 + 2 * ms + s;
    const int b  = tb_abs >> 7;
    const int tb = tb_abs & 127;
    const int hs = tt >> 1;
    const int e  = (lc & 3) + 4 * (tt & 1);
    #pragma unroll
    for (int r = 0; r < 4; ++r) {
      const int lane_c = 4 * lg + r + 16 * (lc >> 2);
      // q
      {
        const float val = aq[s][r];
        const u16 hvv = f2bu(val);
        u16* dst = qpk + (((size_t)(b * 128 + tb) * 4 + hs) * 2 * 64 + lane_c) * 8 + e;
        dst[0]   = hvv;
        dst[512] = f2bu(val - bu2f(hvv));
      }
      // k
      {
        const float val = ak[s][r];
        const u16 hvv = f2bu(val);
        u16* dst = kpk + (((size_t)(b * 128 + tb) * 4 + hs) * 2 * 64 + lane_c) * 8 + e;
        dst[0]   = hvv;
        dst[512] = f2bu(val - bu2f(hvv));
      }
      // v
      {
        const int kt = tb >> 1;
        const int lane_cv = lc + 16 * lg;
        const int ev = r + 4 * (tb & 1);
        vpk[(((size_t)(b * 64 + kt) * 8 + tt) * 64 + lane_cv) * 8 + ev] = f2bu(av[s][r]);
      }
    }
  }
}

// ---------------------------------------------------------------------------
// Kernel 2: causal flash attention (round-4 structure + setprio on MFMA
// clusters). 8 waves, intra-block split-K (kb = w mod 8), 1 q-tile/wave.
// Swapped QK^T so P lands in PV's A-operand layout. LDS combine (bf16).
// ---------------------------------------------------------------------------
__global__ __launch_bounds__(512, 4) void attn_kernel(
    const u16* __restrict__ qpk, const u16* __restrict__ kpk,
    const u16* __restrict__ vpk, float* __restrict__ out) {
  __shared__ float lm[8][16];
  __shared__ float ll[8][16];
  __shared__ u16 lo[8][16][132];     // bf16 partial O

  const int bid = blockIdx.x;
  const int b   = bid & 7;           // batch -> XCD affinity
  const int qt  = bid >> 3;          // 0..127
  const int w    = threadIdx.x >> 6;
  const int lane = threadIdx.x & 63;
  const int lg = lane >> 4, lc = lane & 15;

  // Q fragments: [b][qt][hs][hl][lane][8], tile stride 4096 u16
  Frag bqh[4], bql[4];
  const u16* qp = qpk + (size_t)(b * 128 + qt) * 4096 + lane * 8;
  #pragma unroll
  for (int hs = 0; hs < 4; ++hs) {
    bqh[hs].u4 = *(const u32x4*)(qp + (size_t)(hs * 2 + 0) * 512);
    bql[hs].u4 = *(const u32x4*)(qp + (size_t)(hs * 2 + 1) * 512);
  }

  f32x4 zero = {0.f, 0.f, 0.f, 0.f};
  f32x4 o_acc[8];
  #pragma unroll
  for (int i = 0; i < 8; ++i) o_acc[i] = zero;
  float m_run = -INFINITY, l_run = 0.f;

  const int myq = qt * 16 + lc;
  const int nkb = qt >> 2;           // last 64-wide k-block

  for (int kb = w; kb <= nkb; kb += 8) {
    f32x4 s[4];
    #pragma unroll
    for (int t = 0; t < 4; ++t) s[t] = zero;

    const u16* kp = kpk + (size_t)(b * 128 + kb * 4) * 4096 + lane * 8;
    __builtin_amdgcn_s_setprio(1);
    #pragma unroll
    for (int t = 0; t < 4; ++t) {
      #pragma unroll
      for (int hs = 0; hs < 4; ++hs) {
        const u16* p = kp + (size_t)(t * 8 + hs * 2) * 512;
        Frag akh, akl;
        akh.u4 = *(const u32x4*)p;
        akl.u4 = *(const u32x4*)(p + 512);
        s[t] = MFMA(akh.v, bqh[hs].v, s[t]);
        s[t] = MFMA(akh.v, bql[hs].v, s[t]);
        s[t] = MFMA(akl.v, bqh[hs].v, s[t]);
      }
    }
    __builtin_amdgcn_s_setprio(0);

    // scale by sqrt(C)=32; causal + (tril==0 -> -inf) semantics
    float pmax = -INFINITY;
    #pragma unroll
    for (int t = 0; t < 4; ++t) {
      #pragma unroll
      for (int r = 0; r < 4; ++r) {
        const int kk = kb * 64 + t * 16 + 4 * lg + r;
        float v = s[t][r] * 32.0f;
        if (kk > myq || v == 0.0f) v = -INFINITY;
        s[t][r] = v;
        pmax = fmaxf(pmax, v);
      }
    }
    pmax = fmaxf(pmax, __shfl_xor(pmax, 16));
    pmax = fmaxf(pmax, __shfl_xor(pmax, 32));
    const float m_new = fmaxf(m_run, pmax);
    const float alpha = __expf(m_run - m_new);

    float sum = 0.f;
    u16 pb[16];
    #pragma unroll
    for (int t = 0; t < 4; ++t) {
      #pragma unroll
      for (int r = 0; r < 4; ++r) {
        const float p = __expf(s[t][r] - m_new);
        sum += p;
        pb[t * 4 + r] = f2bu(p);
      }
    }
    sum += __shfl_xor(sum, 16);
    sum += __shfl_xor(sum, 32);
    l_run = l_run * alpha + sum;
    m_run = m_new;

    float al[4];
    #pragma unroll
    for (int r = 0; r < 4; ++r) al[r] = __shfl(alpha, 4 * lg + r);
    #pragma unroll
    for (int i = 0; i < 8; ++i) {
      #pragma unroll
      for (int r = 0; r < 4; ++r) o_acc[i][r] *= al[r];
    }

    Frag pa[2];
    #pragma unroll
    for (int ks = 0; ks < 2; ++ks) {
      #pragma unroll
      for (int e = 0; e < 8; ++e)
        pa[ks].s[e] = pb[(2 * ks + (e >> 2)) * 4 + (e & 3)];
    }

    __builtin_amdgcn_s_setprio(1);
    #pragma unroll
    for (int ks = 0; ks < 2; ++ks) {
      const u16* vp = vpk + (size_t)(b * 64 + kb * 2 + ks) * 4096 + lane * 8;
      #pragma unroll
      for (int ht = 0; ht < 8; ++ht) {
        Frag bv;
        bv.u4 = *(const u32x4*)(vp + (size_t)ht * 512);
        o_acc[ht] = MFMA(pa[ks].v, bv.v, o_acc[ht]);
      }
    }
    __builtin_amdgcn_s_setprio(0);
  }

  // --- combine 8 partials through LDS ---
  if (lane < 16) { lm[w][lane] = m_run; ll[w][lane] = l_run; }
  #pragma unroll
  for (int ht = 0; ht < 8; ++ht)
    #pragma unroll
    for (int r = 0; r < 4; ++r)
      lo[w][4 * lg + r][ht * 16 + lc] = f2bu(o_acc[ht][r]);
  __syncthreads();

  const int tid = threadIdx.x;
  const int q  = tid >> 5;            // 0..15
  const int hb = (tid & 31) * 4;      // 0..124
  float M = -INFINITY;
  #pragma unroll
  for (int ww = 0; ww < 8; ++ww) M = fmaxf(M, lm[ww][q]);
  float lsum = 0.f;
  f32x4 osum = {0.f, 0.f, 0.f, 0.f};
  #pragma unroll
  for (int ww = 0; ww < 8; ++ww) {
    const float sc = __expf(lm[ww][q] - M);
    lsum += sc * ll[ww][q];
    const u16x4 ov = *(const u16x4*)&lo[ww][q][hb];
    #pragma unroll
    for (int j = 0; j < 4; ++j) osum[j] += sc * bu2f(ov[j]);
  }
  const float inv = 1.0f / lsum;
  f32x4 res = {osum[0] * inv, osum[1] * inv, osum[2] * inv, osum[3] * inv};
  *(f32x4*)&out[((size_t)(b * T + qt * 16 + q)) * H + hb] = res;
}

// ---------------------------------------------------------------------------
extern "C" void kernel_launch(void* const* d_in, const int* in_sizes, int n_in,
                              void* d_out, int out_size, void* d_ws, size_t ws_size,
                              hipStream_t stream) {
  (void)in_sizes; (void)n_in; (void)out_size; (void)ws_size;
  const float* x  = (const float*)d_in[0];
  const float* Wk = (const float*)d_in[1];
  const float* Wq = (const float*)d_in[2];
  const float* Wv = (const float*)d_in[3];
  float* out = (float*)d_out;

  u16* w = (u16*)d_ws;
  const size_t WPQK = (size_t)8 * 32 * 2 * 64 * 8;       // 262144
  const size_t WPV  = (size_t)8 * 32 * 64 * 8;           // 131072
  const size_t QKP  = (size_t)NB * 128 * 4 * 2 * 64 * 8; // 4194304
  u16* wpq = w;
  u16* wpk = wpq + WPQK;
  u16* wpv = wpk + WPQK;
  u16* qpk = wpv + WPV;
  u16* kpk = qpk + QKP;
  u16* vpk = kpk + QKP;

  prep_w<<<192, 256, 0, stream>>>(Wk, Wq, Wv, wpq, wpk, wpv);
  proj_kernel<<<512, 512, 0, stream>>>(x, wpq, wpk, wpv, qpk, kpk, vpk);
  attn_kernel<<<NB * (T / 16), 512, 0, stream>>>(qpk, kpk, vpk, out);
}